// Round 12
// baseline (225.992 us; speedup 1.0000x reference)
//
#include <hip/hip_runtime.h>
#include <math.h>

#define C 128
#define NSP 4096  // H*W
#define LOG2E 1.4426950408889634f

typedef __attribute__((ext_vector_type(8))) short short8;
typedef __attribute__((ext_vector_type(4))) float f32x4;
typedef __attribute__((ext_vector_type(16))) float f32x16;

static __device__ __forceinline__ unsigned short f2bf(float f) {
    union { float f; unsigned u; } a; a.f = f;
    unsigned r = a.u + 0x7fffu + ((a.u >> 16) & 1u);
    return (unsigned short)(r >> 16);
}

static __device__ __forceinline__ float bf2f(unsigned short s) {
    union { unsigned u; float f; } a; a.u = (unsigned)s << 16;
    return a.f;
}

// pack two f32 -> bf16x2 (round-half-up); a in low16, b in high16
static __device__ __forceinline__ unsigned pkbf(float a, float b) {
    union { float f; unsigned u; } ua, ub; ua.f = a; ub.f = b;
    return __builtin_amdgcn_perm(ub.u + 0x8000u, ua.u + 0x8000u, 0x07060302u);
}

static __device__ __forceinline__ float ex2(float x) {
#if __has_builtin(__builtin_amdgcn_exp2f)
    return __builtin_amdgcn_exp2f(x);
#else
    return exp2f(x);
#endif
}

static __device__ __forceinline__ f32x4 mfma16(short8 a, short8 b, f32x4 c) {
    // D[row=quad*4+reg][col=lane&15]; A[row=lane&15][k=quad*8+j]; B[k=quad*8+j][col=lane&15]
    return __builtin_amdgcn_mfma_f32_16x16x32_bf16(a, b, c, 0, 0, 0);
}

static __device__ __forceinline__ f32x16 mfma32(short8 a, short8 b, f32x16 c) {
    // D[row=(r&3)+8*(r>>2)+4*(lane>>5)][col=lane&31]
    // A[row=lane&31][k=(lane>>5)*8+j]; B[k=(lane>>5)*8+j][col=lane&31]
    return __builtin_amdgcn_mfma_f32_32x32x16_bf16(a, b, c, 0, 0, 0);
}

// ======================= weight pre-conversion =======================
// All 16 CxC matrices (Wq*log2e, Wk, Wv, Wo x 4 layers) -> bf16 once.
__global__ __launch_bounds__(256)
void prep_kernel(const float* __restrict__ Wq, const float* __restrict__ Wk,
                 const float* __restrict__ Wv, const float* __restrict__ Wo,
                 unsigned short* __restrict__ Wb)
{
    int gid = blockIdx.x * 256 + threadIdx.x;  // 128 blocks -> 32768 threads x 8 elems
    int base = gid * 8;
    int mat = base >> 14;                      // 16384 elems per matrix
    int off = base & 16383;
    const float* src = (mat < 4)  ? (Wq + (size_t)mat * 16384)
                     : (mat < 8)  ? (Wk + (size_t)(mat - 4) * 16384)
                     : (mat < 12) ? (Wv + (size_t)(mat - 8) * 16384)
                                  : (Wo + (size_t)(mat - 12) * 16384);
    float scale = (mat < 4) ? LOG2E : 1.0f;
    float4 v0 = *reinterpret_cast<const float4*>(src + off);
    float4 v1 = *reinterpret_cast<const float4*>(src + off + 4);
    uint4 u;
    u.x = pkbf(v0.x * scale, v0.y * scale);
    u.y = pkbf(v0.z * scale, v0.w * scale);
    u.z = pkbf(v1.x * scale, v1.y * scale);
    u.w = pkbf(v1.z * scale, v1.w * scale);
    *reinterpret_cast<uint4*>(Wb + base) = u;
}

// ---- staging helpers ----
// pure uint4 copy of a pre-converted bf16 [128][128] weight matrix into Wl (pad 136)
static __device__ __forceinline__ void stage_wb(const unsigned short* __restrict__ Wm,
                                                unsigned short* __restrict__ Wl, int t) {
#pragma unroll
    for (int i = 0; i < 8; i++) {
        int idx = i * 256 + t;
        int o = idx >> 4, c8 = (idx & 15) << 3;
        *reinterpret_cast<uint4*>(&Wl[o * 136 + c8]) =
            *reinterpret_cast<const uint4*>(Wm + o * C + c8);
    }
}

// transpose-on-read input staging: In fp32 [c][n] -> Il bf16 [n][c] (pad 136).
// Lane-coalesced dword loads (lanes walk n), ONE b128 LDS write per 8 elems
// (vs 8 float4 + 32 f2bf + 32 scalar u16 writes before).
static __device__ __forceinline__ void stage_in(const float* __restrict__ In, int n0,
                                                unsigned short* __restrict__ Il, int t) {
#pragma unroll
    for (int i = 0; i < 4; i++) {
        int idx = i * 256 + t;
        int n = idx & 63, cb = idx >> 6;   // cb 0..15
        float v[8];
#pragma unroll
        for (int j = 0; j < 8; j++)
            v[j] = In[(size_t)(cb * 8 + j) * NSP + n0 + n];
        uint4 u;
        u.x = pkbf(v[0], v[1]);
        u.y = pkbf(v[2], v[3]);
        u.z = pkbf(v[4], v[5]);
        u.w = pkbf(v[6], v[7]);
        *reinterpret_cast<uint4*>(&Il[n * 136 + cb * 8]) = u;
    }
}

// fused combine+stage for a 32-row tile: Il[n][c] = bf16((sum_k Op_k)/(sum_k L_k))
static __device__ __forceinline__ void stage_sum32(const unsigned short* __restrict__ Op,
                                                   const float* __restrict__ Lp,
                                                   int jb, int nks, int n0,
                                                   unsigned short* __restrict__ Il, int t) {
#pragma unroll
    for (int i = 0; i < 2; i++) {
        int idx = i * 256 + t;
        int n = idx >> 4, c8 = (idx & 15) << 3;
        float o[8];
#pragma unroll
        for (int j = 0; j < 8; j++) o[j] = 0.0f;
        float Ls = 0.0f;
        for (int k = 0; k < nks; k++) {
            size_t kjb = (size_t)(k * 4 + jb);
            Ls += Lp[kjb * NSP + n0 + n];
            union { uint4 v; unsigned short s[8]; } u;
            u.v = *reinterpret_cast<const uint4*>(Op + (kjb * NSP + n0 + n) * C + c8);
#pragma unroll
            for (int j = 0; j < 8; j++) o[j] += bf2f(u.s[j]);
        }
        float inv = 1.0f / Ls;
        union { uint4 v; unsigned u[4]; } w;
        w.u[0] = pkbf(o[0] * inv, o[1] * inv);
        w.u[1] = pkbf(o[2] * inv, o[3] * inv);
        w.u[2] = pkbf(o[4] * inv, o[5] * inv);
        w.u[3] = pkbf(o[6] * inv, o[7] * inv);
        *reinterpret_cast<uint4*>(&Il[n * 136 + c8]) = w.v;
    }
}

// ======================= QKV projection =======================
// out = relu(W @ in + b).  Q,K stored [n][c] bf16 ; V stored [c][n] bf16.
// W pre-converted bf16 (Q pre-scaled by log2e); bias scaled at load for Q.
__global__ __launch_bounds__(256)
void qkv_kernel(const float* __restrict__ qs0, const float* __restrict__ qs1,
                const float* __restrict__ kv0, const float* __restrict__ kv1,
                const unsigned short* __restrict__ Wb,
                const float* __restrict__ bq, const float* __restrict__ bk,
                const float* __restrict__ bv,
                int layer_base,
                unsigned short* __restrict__ Qb, unsigned short* __restrict__ Kb,
                unsigned short* __restrict__ Vb)
{
    __shared__ __align__(16) unsigned short Wl[128 * 136];
    __shared__ __align__(16) unsigned short Il[64 * 136];
    const int t = threadIdx.x;
    const int ntile = blockIdx.x, kind = blockIdx.y, jb = blockIdx.z;
    const int job = jb >> 1, b = jb & 1, layer = layer_base + job;
    const float* src = (kind == 0) ? (job ? qs1 : qs0) : (job ? kv1 : kv0);
    const float* In = src + (size_t)b * C * NSP;
    const unsigned short* Wm = Wb + (size_t)(kind * 4 + layer) * 16384;
    const float* bias = ((kind == 0) ? bq : (kind == 1) ? bk : bv) + layer * C;
    unsigned short* Out = ((kind == 0) ? Qb : (kind == 1) ? Kb : Vb) + (size_t)jb * NSP * C;
    const float scale = (kind == 0) ? LOG2E : 1.0f;
    const int n0 = ntile * 64;

    stage_wb(Wm, Wl, t);
    stage_in(In, n0, Il, t);
    __syncthreads();

    const int lane = t & 63, w = t >> 6, l15 = lane & 15, quad = lane >> 4;

    if (kind <= 1) {
        f32x4 acc[4][2];
#pragma unroll
        for (int nt = 0; nt < 4; nt++)
#pragma unroll
            for (int ot = 0; ot < 2; ot++)
#pragma unroll
                for (int r = 0; r < 4; r++) acc[nt][ot][r] = 0.0f;
#pragma unroll
        for (int ks = 0; ks < 4; ks++) {
            int co = ks * 32 + quad * 8;
            short8 b0 = *reinterpret_cast<const short8*>(&Wl[(w * 32 + l15) * 136 + co]);
            short8 b1 = *reinterpret_cast<const short8*>(&Wl[(w * 32 + 16 + l15) * 136 + co]);
#pragma unroll
            for (int nt = 0; nt < 4; nt++) {
                short8 a = *reinterpret_cast<const short8*>(&Il[(nt * 16 + l15) * 136 + co]);
                acc[nt][0] = mfma16(a, b0, acc[nt][0]);
                acc[nt][1] = mfma16(a, b1, acc[nt][1]);
            }
        }
        float bz0 = bias[w * 32 + l15] * scale;
        float bz1 = bias[w * 32 + 16 + l15] * scale;
#pragma unroll
        for (int nt = 0; nt < 4; nt++)
#pragma unroll
            for (int ot = 0; ot < 2; ot++)
#pragma unroll
                for (int r = 0; r < 4; r++) {
                    float v = fmaxf(acc[nt][ot][r] + (ot ? bz1 : bz0), 0.0f);
                    int n = n0 + nt * 16 + quad * 4 + r;
                    int o = w * 32 + ot * 16 + l15;
                    Out[(size_t)n * C + o] = f2bf(v);
                }
    } else {
        f32x4 acc[2][4];
#pragma unroll
        for (int ot = 0; ot < 2; ot++)
#pragma unroll
            for (int nt = 0; nt < 4; nt++)
#pragma unroll
                for (int r = 0; r < 4; r++) acc[ot][nt][r] = 0.0f;
#pragma unroll
        for (int ks = 0; ks < 4; ks++) {
            int co = ks * 32 + quad * 8;
            short8 a0 = *reinterpret_cast<const short8*>(&Wl[(w * 32 + l15) * 136 + co]);
            short8 a1 = *reinterpret_cast<const short8*>(&Wl[(w * 32 + 16 + l15) * 136 + co]);
#pragma unroll
            for (int nt = 0; nt < 4; nt++) {
                short8 bb = *reinterpret_cast<const short8*>(&Il[(nt * 16 + l15) * 136 + co]);
                acc[0][nt] = mfma16(a0, bb, acc[0][nt]);
                acc[1][nt] = mfma16(a1, bb, acc[1][nt]);
            }
        }
#pragma unroll
        for (int ot = 0; ot < 2; ot++)
#pragma unroll
            for (int r = 0; r < 4; r++) {
                int o = w * 32 + ot * 16 + quad * 4 + r;
                float bz = bias[o];
#pragma unroll
                for (int nt = 0; nt < 4; nt++) {
                    float v = fmaxf(acc[ot][nt][r] + bz, 0.0f);
                    Out[(size_t)o * NSP + n0 + nt * 16 + l15] = f2bf(v);
                }
            }
    }
}

// ======================= attention, no-max softmax, split-K over keys =======================
// R10's 8-wave/32x32/in-register-P structure with KVBLK=64: two 32-key
// sub-phases per LDS tile -> ONE barrier per 64 keys (was per 32). Same
// register body (s reused across sub-phases; only kreg/vreg double, +16 VGPR,
// still 1 WG/CU which is the register-granular limit). V pad 72 preserves the
// verified pad-40 bank profile (stride = 4*l31 mod 32 both).
__global__ __launch_bounds__(512)
void attn_kernel(const unsigned short* __restrict__ Qb, const unsigned short* __restrict__ Kb,
                 const unsigned short* __restrict__ Vb, unsigned short* __restrict__ Op,
                 float* __restrict__ Lp, int iters)
{
    __shared__ __align__(16) unsigned short Kl[2][64 * 136];   // 2 x 17408 B  [m][c]
    __shared__ __align__(16) unsigned short Vl[2][128 * 72];   // 2 x 18432 B  [c][m]
    const int t = threadIdx.x, lane = t & 63;
    const int l31 = lane & 31, hi = lane >> 5;

    // XCD-bijective swizzle (nwg = 16*4*ks, divisible by 8), jb-outer/kc-inner
    const int ksz = gridDim.z;
    const int nwg = gridDim.x * gridDim.y * ksz;
    const int linear = blockIdx.x + gridDim.x * (blockIdx.y + gridDim.y * blockIdx.z);
    const int cpx = nwg >> 3;
    const int wid = (linear & 7) * cpx + (linear >> 3);
    const int ntile = wid & 15;
    const int r2 = wid >> 4;
    const int jb = r2 / ksz, kc = r2 % ksz;

    const int n0 = ntile * 256 + (t >> 6) * 32;
    const int m_begin = kc * iters * 64;
    const unsigned short* Q = Qb + (size_t)jb * NSP * C;
    const unsigned short* K = Kb + (size_t)jb * NSP * C;
    const unsigned short* V = Vb + (size_t)jb * NSP * C;  // [c][n]

    // Q fragments (B-operand of S): B[k=hi*8+j][col=n=l31], k = channel
    short8 qf[8];
#pragma unroll
    for (int ks = 0; ks < 8; ks++)
        qf[ks] = *reinterpret_cast<const short8*>(
            Q + (size_t)(n0 + l31) * C + ks * 16 + hi * 8);

    f32x16 o_acc[4];
#pragma unroll
    for (int ct = 0; ct < 4; ct++)
#pragma unroll
        for (int r = 0; r < 16; r++) o_acc[ct][r] = 0.0f;
    float L = 0.0f;

    // 512 threads: two uint4 of K + two of V per thread per 64-key tile
    uint4 kreg[2], vreg[2];

#define ATT_LOAD(BLK)                                                                     \
    {                                                                                     \
        int mb_ = m_begin + (BLK) * 64;                                                   \
        _Pragma("unroll") for (int i = 0; i < 2; i++) {                                   \
            int idx = i * 512 + t;                                                        \
            int m_ = idx >> 4, c8_ = (idx & 15) << 3;                                     \
            kreg[i] = *reinterpret_cast<const uint4*>(K + (size_t)(mb_ + m_) * C + c8_);  \
            int c_ = idx >> 3, m8_ = (idx & 7) << 3;                                      \
            vreg[i] = *reinterpret_cast<const uint4*>(V + (size_t)c_ * NSP + mb_ + m8_);  \
        }                                                                                 \
    }

#define ATT_STORE(BUF)                                                                    \
    {                                                                                     \
        _Pragma("unroll") for (int i = 0; i < 2; i++) {                                   \
            int idx = i * 512 + t;                                                        \
            int m_ = idx >> 4, c8_ = (idx & 15) << 3;                                     \
            *reinterpret_cast<uint4*>(&Kl[BUF][m_ * 136 + c8_]) = kreg[i];                \
            int c_ = idx >> 3, m8_ = (idx & 7) << 3;                                      \
            *reinterpret_cast<uint4*>(&Vl[BUF][c_ * 72 + m8_]) = vreg[i];                 \
        }                                                                                 \
    }

    // prologue: tile 0 -> buf 0; prefetch tile 1 into regs
    ATT_LOAD(0);
    ATT_STORE(0);
    if (iters > 1) ATT_LOAD(1);
    __syncthreads();

    int cur = 0;
    for (int blk = 0; blk < iters; blk++) {
        const unsigned short* Kc = &Kl[cur][0];
        const unsigned short* Vc = &Vl[cur][0];

#pragma unroll
        for (int h = 0; h < 2; h++) {
            // S^T[m][n] (32x32): A = K rows (m = h*32+l31), B = Q cols (n = l31)
            f32x16 s;
#pragma unroll
            for (int r = 0; r < 16; r++) s[r] = 0.0f;
            __builtin_amdgcn_s_setprio(1);
#pragma unroll
            for (int ks = 0; ks < 8; ks++) {
                short8 ka = *reinterpret_cast<const short8*>(
                    &Kc[(h * 32 + l31) * 136 + ks * 16 + hi * 8]);
                s = mfma32(ka, qf[ks], s);
            }
            __builtin_amdgcn_s_setprio(0);

            // mid-iter (once, after first sub-phase's S): commit tile blk+1 into
            // buf cur^1, reissue loads for blk+2 (cover = rest of iter + barrier)
            if (h == 0 && blk + 1 < iters) {
                ATT_STORE(cur ^ 1);
                if (blk + 2 < iters) ATT_LOAD(blk + 2);
            }

            // P = exp2(S) in place, accumulate L
            float ls = 0.0f;
#pragma unroll
            for (int r = 0; r < 16; r++) {
                s[r] = ex2(s[r]);
                ls += s[r];
            }
            L += ls;

            // in-register P -> PV B-fragments via permlane32_swap (T12)
            unsigned a0 = pkbf(s[0], s[1]),  a1 = pkbf(s[2], s[3]);
            unsigned b0 = pkbf(s[4], s[5]),  b1 = pkbf(s[6], s[7]);
            unsigned c0 = pkbf(s[8], s[9]),  c1 = pkbf(s[10], s[11]);
            unsigned d0 = pkbf(s[12], s[13]), d1 = pkbf(s[14], s[15]);
            asm("v_permlane32_swap_b32 %0, %1" : "+v"(a0), "+v"(b0));
            asm("v_permlane32_swap_b32 %0, %1" : "+v"(a1), "+v"(b1));
            asm("v_permlane32_swap_b32 %0, %1" : "+v"(c0), "+v"(d0));
            asm("v_permlane32_swap_b32 %0, %1" : "+v"(c1), "+v"(d1));
            union { uint4 u; short8 s8; } f0u, f1u;
            f0u.u = make_uint4(a0, a1, b0, b1);  // m = h*32 +  0..15
            f1u.u = make_uint4(c0, c1, d0, d1);  // m = h*32 + 16..31

            // O^T[c][n] += V[c][m] * P^T[m][n]
            __builtin_amdgcn_s_setprio(1);
#pragma unroll
            for (int ct = 0; ct < 4; ct++) {
                short8 v0 = *reinterpret_cast<const short8*>(
                    &Vc[(ct * 32 + l31) * 72 + h * 32 + hi * 8]);
                short8 v1 = *reinterpret_cast<const short8*>(
                    &Vc[(ct * 32 + l31) * 72 + h * 32 + 16 + hi * 8]);
                o_acc[ct] = mfma32(v0, f0u.s8, o_acc[ct]);
                o_acc[ct] = mfma32(v1, f1u.s8, o_acc[ct]);
            }
            __builtin_amdgcn_s_setprio(0);
        }

        __syncthreads();  // ONE barrier per 64-key tile
        cur ^= 1;
    }

#undef ATT_LOAD
#undef ATT_STORE

    // epilogue: L reduce + partial O store ([n][c] bf16)
    const size_t kjb = (size_t)(kc * 4 + jb);
    float Lv = L + __shfl_xor(L, 32);
    if (lane < 32) Lp[kjb * NSP + n0 + l31] = Lv;

    unsigned short* Ob = Op + kjb * NSP * C;  // [n][c]
    const int n = n0 + l31;
    unsigned short* On = Ob + (size_t)n * C + hi * 4;
#pragma unroll
    for (int ct = 0; ct < 4; ct++)
#pragma unroll
        for (int rb = 0; rb < 4; rb++) {
            int r0 = rb * 4;
            uint2 u;
            u.x = pkbf(o_acc[ct][r0 + 0], o_acc[ct][r0 + 1]);
            u.y = pkbf(o_acc[ct][r0 + 2], o_acc[ct][r0 + 3]);
            *reinterpret_cast<uint2*>(On + ct * 32 + rb * 8) = u;
        }
}

// ======================= output projection + residual (pass 1) =======================
__global__ __launch_bounds__(256)
void proj_kernel(const unsigned short* __restrict__ Op, const float* __restrict__ Lp, int nks,
                 const unsigned short* __restrict__ Wb,
                 const float* __restrict__ bo, int layer_base,
                 const float* __restrict__ res0, const float* __restrict__ res1,
                 float* __restrict__ out0, float* __restrict__ out1)
{
    __shared__ __align__(16) unsigned short Wl[128 * 136];
    __shared__ __align__(16) unsigned short Il[32 * 136];
    const int t = threadIdx.x;
    const int ntile = blockIdx.x, jb = blockIdx.y;
    const int job = jb >> 1, b = jb & 1, layer = layer_base + job;
    const float* bias = bo + layer * C;
    const float* res = (job ? res1 : res0) + (size_t)b * C * NSP;
    float* out = (job ? out1 : out0) + (size_t)b * C * NSP;
    const int n0 = ntile * 32;

    stage_wb(Wb + (size_t)(12 + layer) * 16384, Wl, t);
    stage_sum32(Op, Lp, jb, nks, n0, Il, t);
    __syncthreads();

    const int lane = t & 63, w = t >> 6, l15 = lane & 15, quad = lane >> 4;
    f32x4 acc[2][2];
#pragma unroll
    for (int ot = 0; ot < 2; ot++)
#pragma unroll
        for (int nt = 0; nt < 2; nt++)
#pragma unroll
            for (int r = 0; r < 4; r++) acc[ot][nt][r] = 0.0f;
#pragma unroll
    for (int ks = 0; ks < 4; ks++) {
        int co = ks * 32 + quad * 8;
        short8 a0 = *reinterpret_cast<const short8*>(&Wl[(w * 32 + l15) * 136 + co]);
        short8 a1 = *reinterpret_cast<const short8*>(&Wl[(w * 32 + 16 + l15) * 136 + co]);
#pragma unroll
        for (int nt = 0; nt < 2; nt++) {
            short8 bb = *reinterpret_cast<const short8*>(&Il[(nt * 16 + l15) * 136 + co]);
            acc[0][nt] = mfma16(a0, bb, acc[0][nt]);
            acc[1][nt] = mfma16(a1, bb, acc[1][nt]);
        }
    }
#pragma unroll
    for (int ot = 0; ot < 2; ot++)
#pragma unroll
        for (int r = 0; r < 4; r++) {
            int o = w * 32 + ot * 16 + quad * 4 + r;
            float bz = bias[o];
#pragma unroll
            for (int nt = 0; nt < 2; nt++) {
                int n = n0 + nt * 16 + l15;
                float v = fmaxf(acc[ot][nt][r] + bz, 0.0f) + res[(size_t)o * NSP + n];
                out[(size_t)o * NSP + n] = v;
            }
        }
}

// ======================= final: both jobs summed into d_out =======================
__global__ __launch_bounds__(256)
void final_kernel(const unsigned short* __restrict__ Op, const float* __restrict__ Lp, int nks,
                  const unsigned short* __restrict__ Wb,
                  const float* __restrict__ bo,
                  const float* __restrict__ fuse0, const float* __restrict__ fuse1,
                  float* __restrict__ out)
{
    __shared__ __align__(16) unsigned short Wl[128 * 136];
    __shared__ __align__(16) unsigned short Il[32 * 136];
    const int t = threadIdx.x;
    const int ntile = blockIdx.x, b = blockIdx.y;
    const int n0 = ntile * 32;
    const int lane = t & 63, w = t >> 6, l15 = lane & 15, quad = lane >> 4;

    float tot[2][2][4];
#pragma unroll
    for (int ot = 0; ot < 2; ot++)
#pragma unroll
        for (int nt = 0; nt < 2; nt++)
#pragma unroll
            for (int r = 0; r < 4; r++) tot[ot][nt][r] = 0.0f;

    for (int j = 0; j < 2; j++) {
        if (j) __syncthreads();
        int layer = 2 + j;
        stage_wb(Wb + (size_t)(12 + layer) * 16384, Wl, t);
        stage_sum32(Op, Lp, j * 2 + b, nks, n0, Il, t);
        __syncthreads();

        f32x4 acc[2][2];
#pragma unroll
        for (int ot = 0; ot < 2; ot++)
#pragma unroll
            for (int nt = 0; nt < 2; nt++)
#pragma unroll
                for (int r = 0; r < 4; r++) acc[ot][nt][r] = 0.0f;
#pragma unroll
        for (int ks = 0; ks < 4; ks++) {
            int co = ks * 32 + quad * 8;
            short8 a0 = *reinterpret_cast<const short8*>(&Wl[(w * 32 + l15) * 136 + co]);
            short8 a1 = *reinterpret_cast<const short8*>(&Wl[(w * 32 + 16 + l15) * 136 + co]);
#pragma unroll
            for (int nt = 0; nt < 2; nt++) {
                short8 bb = *reinterpret_cast<const short8*>(&Il[(nt * 16 + l15) * 136 + co]);
                acc[0][nt] = mfma16(a0, bb, acc[0][nt]);
                acc[1][nt] = mfma16(a1, bb, acc[1][nt]);
            }
        }
        const float* bias = bo + layer * C;
        const float* fuse = (j ? fuse1 : fuse0) + (size_t)b * C * NSP;
#pragma unroll
        for (int ot = 0; ot < 2; ot++)
#pragma unroll
            for (int r = 0; r < 4; r++) {
                int o = w * 32 + ot * 16 + quad * 4 + r;
                float bz = bias[o];
#pragma unroll
                for (int nt = 0; nt < 2; nt++) {
                    int n = n0 + nt * 16 + l15;
                    tot[ot][nt][r] += fmaxf(acc[ot][nt][r] + bz, 0.0f) + fuse[(size_t)o * NSP + n];
                }
            }
    }
#pragma unroll
    for (int ot = 0; ot < 2; ot++)
#pragma unroll
        for (int r = 0; r < 4; r++) {
            int o = w * 32 + ot * 16 + quad * 4 + r;
#pragma unroll
            for (int nt = 0; nt < 2; nt++) {
                int n = n0 + nt * 16 + l15;
                out[(size_t)b * C * NSP + (size_t)o * NSP + n] = tot[ot][nt][r];
            }
        }
}

extern "C" void kernel_launch(void* const* d_in, const int* in_sizes, int n_in,
                              void* d_out, int out_size, void* d_ws, size_t ws_size,
                              hipStream_t stream)
{
    (void)in_sizes; (void)n_in; (void)out_size;
    const float* x  = (const float*)d_in[0];
    const float* y  = (const float*)d_in[1];
    const float* Wq = (const float*)d_in[2];
    const float* bq = (const float*)d_in[3];
    const float* Wk = (const float*)d_in[4];
    const float* bk = (const float*)d_in[5];
    const float* Wv = (const float*)d_in[6];
    const float* bv = (const float*)d_in[7];
    const float* Wo = (const float*)d_in[8];
    const float* bo = (const float*)d_in[9];
    float* out = (float*)d_out;
    char* ws = (char*)d_ws;

    // split-K factor: ks=4 -> grid 16*4*4 = 256 WGs = one round at 1 WG/CU.
    // iters = 64-key tiles per kc = NSP/(64*ks).
    int ks = (ws_size >= 38010880u) ? 4 : 2;
    int iters = 64 / ks;

    unsigned short* Qb = (unsigned short*)(ws);               // 4 MB [jb][n][c]
    unsigned short* Kb = (unsigned short*)(ws + (4u << 20));  // 4 MB [jb][n][c]
    unsigned short* Vb = (unsigned short*)(ws + (8u << 20));  // 4 MB [jb][c][n]
    unsigned short* Op = (unsigned short*)(ws + (12u << 20)); // ks*4 MB [k][jb][n][c] bf16
    size_t op_bytes = (size_t)ks * 4 * NSP * C * 2;
    float* Lp = (float*)(ws + (12u << 20) + op_bytes);        // ks*64 KB [k*4+jb][n]
    float* fuse0 = Lp + (size_t)ks * 4 * NSP;                 // 4 MB [b][c][n] fp32
    float* fuse1 = fuse0 + (size_t)2 * C * NSP;               // 4 MB
    unsigned short* Wb = (unsigned short*)(fuse1 + (size_t)2 * C * NSP);  // 512 KB bf16 x16 mats

    // weight pre-conversion (once per launch)
    prep_kernel<<<dim3(128), 256, 0, stream>>>(Wq, Wk, Wv, Wo, Wb);

    // pass 1: L0 (Q from x, KV from y), L1 (Q from y, KV from x)
    qkv_kernel<<<dim3(64, 3, 4), 256, 0, stream>>>(x, y, y, x, Wb, bq, bk, bv, 0,
                                                   Qb, Kb, Vb);
    attn_kernel<<<dim3(16, 4, ks), 512, 0, stream>>>(Qb, Kb, Vb, Op, Lp, iters);
    proj_kernel<<<dim3(128, 4), 256, 0, stream>>>(Op, Lp, ks, Wb, bo, 0, x, y, fuse0, fuse1);

    // pass 2: L2 (all from fuse_xy), L3 (all from fuse_yz)
    qkv_kernel<<<dim3(64, 3, 4), 256, 0, stream>>>(fuse0, fuse1, fuse0, fuse1, Wb,
                                                   bq, bk, bv, 2, Qb, Kb, Vb);
    attn_kernel<<<dim3(16, 4, ks), 512, 0, stream>>>(Qb, Kb, Vb, Op, Lp, iters);
    final_kernel<<<dim3(128, 2), 256, 0, stream>>>(Op, Lp, ks, Wb, bo, fuse0, fuse1, out);
}

// Round 13
// 186.209 us; speedup vs baseline: 1.2136x; 1.2136x over previous
//
#include <hip/hip_runtime.h>
#include <math.h>

#define C 128
#define NSP 4096  // H*W
#define LOG2E 1.4426950408889634f

typedef __attribute__((ext_vector_type(8))) short short8;
typedef __attribute__((ext_vector_type(4))) float f32x4;
typedef __attribute__((ext_vector_type(16))) float f32x16;

static __device__ __forceinline__ unsigned short f2bf(float f) {
    union { float f; unsigned u; } a; a.f = f;
    unsigned r = a.u + 0x7fffu + ((a.u >> 16) & 1u);
    return (unsigned short)(r >> 16);
}

static __device__ __forceinline__ float bf2f(unsigned short s) {
    union { unsigned u; float f; } a; a.u = (unsigned)s << 16;
    return a.f;
}

// pack two f32 -> bf16x2 (round-half-up); a in low16, b in high16
static __device__ __forceinline__ unsigned pkbf(float a, float b) {
    union { float f; unsigned u; } ua, ub; ua.f = a; ub.f = b;
    return __builtin_amdgcn_perm(ub.u + 0x8000u, ua.u + 0x8000u, 0x07060302u);
}

static __device__ __forceinline__ float ex2(float x) {
#if __has_builtin(__builtin_amdgcn_exp2f)
    return __builtin_amdgcn_exp2f(x);
#else
    return exp2f(x);
#endif
}

static __device__ __forceinline__ f32x4 mfma16(short8 a, short8 b, f32x4 c) {
    // D[row=quad*4+reg][col=lane&15]; A[row=lane&15][k=quad*8+j]; B[k=quad*8+j][col=lane&15]
    return __builtin_amdgcn_mfma_f32_16x16x32_bf16(a, b, c, 0, 0, 0);
}

static __device__ __forceinline__ f32x16 mfma32(short8 a, short8 b, f32x16 c) {
    // D[row=(r&3)+8*(r>>2)+4*(lane>>5)][col=lane&31]
    // A[row=lane&31][k=(lane>>5)*8+j]; B[k=(lane>>5)*8+j][col=lane&31]
    return __builtin_amdgcn_mfma_f32_32x32x16_bf16(a, b, c, 0, 0, 0);
}

// ======================= weight pre-conversion =======================
// All 16 CxC matrices (Wq*log2e, Wk, Wv, Wo x 4 layers) -> bf16 once.
__global__ __launch_bounds__(256)
void prep_kernel(const float* __restrict__ Wq, const float* __restrict__ Wk,
                 const float* __restrict__ Wv, const float* __restrict__ Wo,
                 unsigned short* __restrict__ Wb)
{
    int gid = blockIdx.x * 256 + threadIdx.x;  // 128 blocks -> 32768 threads x 8 elems
    int base = gid * 8;
    int mat = base >> 14;                      // 16384 elems per matrix
    int off = base & 16383;
    const float* src = (mat < 4)  ? (Wq + (size_t)mat * 16384)
                     : (mat < 8)  ? (Wk + (size_t)(mat - 4) * 16384)
                     : (mat < 12) ? (Wv + (size_t)(mat - 8) * 16384)
                                  : (Wo + (size_t)(mat - 12) * 16384);
    float scale = (mat < 4) ? LOG2E : 1.0f;
    float4 v0 = *reinterpret_cast<const float4*>(src + off);
    float4 v1 = *reinterpret_cast<const float4*>(src + off + 4);
    uint4 u;
    u.x = pkbf(v0.x * scale, v0.y * scale);
    u.y = pkbf(v0.z * scale, v0.w * scale);
    u.z = pkbf(v1.x * scale, v1.y * scale);
    u.w = pkbf(v1.z * scale, v1.w * scale);
    *reinterpret_cast<uint4*>(Wb + base) = u;
}

// ---- staging helpers ----
// pure uint4 copy of a pre-converted bf16 [128][128] weight matrix into Wl (pad 136)
static __device__ __forceinline__ void stage_wb(const unsigned short* __restrict__ Wm,
                                                unsigned short* __restrict__ Wl, int t) {
#pragma unroll
    for (int i = 0; i < 8; i++) {
        int idx = i * 256 + t;
        int o = idx >> 4, c8 = (idx & 15) << 3;
        *reinterpret_cast<uint4*>(&Wl[o * 136 + c8]) =
            *reinterpret_cast<const uint4*>(Wm + o * C + c8);
    }
}

// transpose-on-read input staging: In fp32 [c][n] -> Il bf16 [n][c] (pad 136).
// Lane-coalesced dword loads (lanes walk n), ONE b128 LDS write per 8 elems.
static __device__ __forceinline__ void stage_in(const float* __restrict__ In, int n0,
                                                unsigned short* __restrict__ Il, int t) {
#pragma unroll
    for (int i = 0; i < 4; i++) {
        int idx = i * 256 + t;
        int n = idx & 63, cb = idx >> 6;   // cb 0..15
        float v[8];
#pragma unroll
        for (int j = 0; j < 8; j++)
            v[j] = In[(size_t)(cb * 8 + j) * NSP + n0 + n];
        uint4 u;
        u.x = pkbf(v[0], v[1]);
        u.y = pkbf(v[2], v[3]);
        u.z = pkbf(v[4], v[5]);
        u.w = pkbf(v[6], v[7]);
        *reinterpret_cast<uint4*>(&Il[n * 136 + cb * 8]) = u;
    }
}

// fused combine+stage for a 32-row tile: Il[n][c] = bf16((sum_k Op_k)/(sum_k L_k))
static __device__ __forceinline__ void stage_sum32(const unsigned short* __restrict__ Op,
                                                   const float* __restrict__ Lp,
                                                   int jb, int nks, int n0,
                                                   unsigned short* __restrict__ Il, int t) {
#pragma unroll
    for (int i = 0; i < 2; i++) {
        int idx = i * 256 + t;
        int n = idx >> 4, c8 = (idx & 15) << 3;
        float o[8];
#pragma unroll
        for (int j = 0; j < 8; j++) o[j] = 0.0f;
        float Ls = 0.0f;
        for (int k = 0; k < nks; k++) {
            size_t kjb = (size_t)(k * 4 + jb);
            Ls += Lp[kjb * NSP + n0 + n];
            union { uint4 v; unsigned short s[8]; } u;
            u.v = *reinterpret_cast<const uint4*>(Op + (kjb * NSP + n0 + n) * C + c8);
#pragma unroll
            for (int j = 0; j < 8; j++) o[j] += bf2f(u.s[j]);
        }
        float inv = 1.0f / Ls;
        union { uint4 v; unsigned u[4]; } w;
        w.u[0] = pkbf(o[0] * inv, o[1] * inv);
        w.u[1] = pkbf(o[2] * inv, o[3] * inv);
        w.u[2] = pkbf(o[4] * inv, o[5] * inv);
        w.u[3] = pkbf(o[6] * inv, o[7] * inv);
        *reinterpret_cast<uint4*>(&Il[n * 136 + c8]) = w.v;
    }
}

// ======================= QKV projection =======================
// out = relu(W @ in + b).  Q,K stored [n][c] bf16 ; V stored [c][n] bf16.
// W pre-converted bf16 (Q pre-scaled by log2e); bias scaled at load for Q.
__global__ __launch_bounds__(256)
void qkv_kernel(const float* __restrict__ qs0, const float* __restrict__ qs1,
                const float* __restrict__ kv0, const float* __restrict__ kv1,
                const unsigned short* __restrict__ Wb,
                const float* __restrict__ bq, const float* __restrict__ bk,
                const float* __restrict__ bv,
                int layer_base,
                unsigned short* __restrict__ Qb, unsigned short* __restrict__ Kb,
                unsigned short* __restrict__ Vb)
{
    __shared__ __align__(16) unsigned short Wl[128 * 136];
    __shared__ __align__(16) unsigned short Il[64 * 136];
    const int t = threadIdx.x;
    const int ntile = blockIdx.x, kind = blockIdx.y, jb = blockIdx.z;
    const int job = jb >> 1, b = jb & 1, layer = layer_base + job;
    const float* src = (kind == 0) ? (job ? qs1 : qs0) : (job ? kv1 : kv0);
    const float* In = src + (size_t)b * C * NSP;
    const unsigned short* Wm = Wb + (size_t)(kind * 4 + layer) * 16384;
    const float* bias = ((kind == 0) ? bq : (kind == 1) ? bk : bv) + layer * C;
    unsigned short* Out = ((kind == 0) ? Qb : (kind == 1) ? Kb : Vb) + (size_t)jb * NSP * C;
    const float scale = (kind == 0) ? LOG2E : 1.0f;
    const int n0 = ntile * 64;

    stage_wb(Wm, Wl, t);
    stage_in(In, n0, Il, t);
    __syncthreads();

    const int lane = t & 63, w = t >> 6, l15 = lane & 15, quad = lane >> 4;

    if (kind <= 1) {
        f32x4 acc[4][2];
#pragma unroll
        for (int nt = 0; nt < 4; nt++)
#pragma unroll
            for (int ot = 0; ot < 2; ot++)
#pragma unroll
                for (int r = 0; r < 4; r++) acc[nt][ot][r] = 0.0f;
#pragma unroll
        for (int ks = 0; ks < 4; ks++) {
            int co = ks * 32 + quad * 8;
            short8 b0 = *reinterpret_cast<const short8*>(&Wl[(w * 32 + l15) * 136 + co]);
            short8 b1 = *reinterpret_cast<const short8*>(&Wl[(w * 32 + 16 + l15) * 136 + co]);
#pragma unroll
            for (int nt = 0; nt < 4; nt++) {
                short8 a = *reinterpret_cast<const short8*>(&Il[(nt * 16 + l15) * 136 + co]);
                acc[nt][0] = mfma16(a, b0, acc[nt][0]);
                acc[nt][1] = mfma16(a, b1, acc[nt][1]);
            }
        }
        float bz0 = bias[w * 32 + l15] * scale;
        float bz1 = bias[w * 32 + 16 + l15] * scale;
#pragma unroll
        for (int nt = 0; nt < 4; nt++)
#pragma unroll
            for (int ot = 0; ot < 2; ot++)
#pragma unroll
                for (int r = 0; r < 4; r++) {
                    float v = fmaxf(acc[nt][ot][r] + (ot ? bz1 : bz0), 0.0f);
                    int n = n0 + nt * 16 + quad * 4 + r;
                    int o = w * 32 + ot * 16 + l15;
                    Out[(size_t)n * C + o] = f2bf(v);
                }
    } else {
        f32x4 acc[2][4];
#pragma unroll
        for (int ot = 0; ot < 2; ot++)
#pragma unroll
            for (int nt = 0; nt < 4; nt++)
#pragma unroll
                for (int r = 0; r < 4; r++) acc[ot][nt][r] = 0.0f;
#pragma unroll
        for (int ks = 0; ks < 4; ks++) {
            int co = ks * 32 + quad * 8;
            short8 a0 = *reinterpret_cast<const short8*>(&Wl[(w * 32 + l15) * 136 + co]);
            short8 a1 = *reinterpret_cast<const short8*>(&Wl[(w * 32 + 16 + l15) * 136 + co]);
#pragma unroll
            for (int nt = 0; nt < 4; nt++) {
                short8 bb = *reinterpret_cast<const short8*>(&Il[(nt * 16 + l15) * 136 + co]);
                acc[0][nt] = mfma16(a0, bb, acc[0][nt]);
                acc[1][nt] = mfma16(a1, bb, acc[1][nt]);
            }
        }
#pragma unroll
        for (int ot = 0; ot < 2; ot++)
#pragma unroll
            for (int r = 0; r < 4; r++) {
                int o = w * 32 + ot * 16 + quad * 4 + r;
                float bz = bias[o];
#pragma unroll
                for (int nt = 0; nt < 4; nt++) {
                    float v = fmaxf(acc[ot][nt][r] + bz, 0.0f);
                    Out[(size_t)o * NSP + n0 + nt * 16 + l15] = f2bf(v);
                }
            }
    }
}

// ======================= attention, no-max softmax, split-K over keys =======================
// R10/R11's verified 46.3us shape (measured 3x): 8 waves/512 thr, KVBLK=32,
// 32x32 MFMA, in-register P via permlane32_swap (T12), double-buffered
// coalesced K/V staging, one barrier per 32-key tile, 2-deep load pipeline,
// ks=4 -> 256 WGs = one round at 1 WG/CU. (R12's KVBLK=64 spilled one f32x16
// per thread -> +8MB scratch writes, 46->67us. Reverted.)
__global__ __launch_bounds__(512)
void attn_kernel(const unsigned short* __restrict__ Qb, const unsigned short* __restrict__ Kb,
                 const unsigned short* __restrict__ Vb, unsigned short* __restrict__ Op,
                 float* __restrict__ Lp, int iters)
{
    __shared__ __align__(16) unsigned short Kl[2][32 * 136];   // 2 x 8704 B  [m][c]
    __shared__ __align__(16) unsigned short Vl[2][128 * 40];   // 2 x 10240 B [c][m]
    const int t = threadIdx.x, lane = t & 63;
    const int l31 = lane & 31, hi = lane >> 5;

    // XCD-bijective swizzle (nwg = 16*4*ks, divisible by 8), jb-outer/kc-inner
    const int ksz = gridDim.z;
    const int nwg = gridDim.x * gridDim.y * ksz;
    const int linear = blockIdx.x + gridDim.x * (blockIdx.y + gridDim.y * blockIdx.z);
    const int cpx = nwg >> 3;
    const int wid = (linear & 7) * cpx + (linear >> 3);
    const int ntile = wid & 15;
    const int r2 = wid >> 4;
    const int jb = r2 / ksz, kc = r2 % ksz;

    const int n0 = ntile * 256 + (t >> 6) * 32;
    const int m_begin = kc * iters * 32;
    const unsigned short* Q = Qb + (size_t)jb * NSP * C;
    const unsigned short* K = Kb + (size_t)jb * NSP * C;
    const unsigned short* V = Vb + (size_t)jb * NSP * C;  // [c][n]

    // Q fragments (B-operand of S): B[k=hi*8+j][col=n=l31], k = channel
    short8 qf[8];
#pragma unroll
    for (int ks = 0; ks < 8; ks++)
        qf[ks] = *reinterpret_cast<const short8*>(
            Q + (size_t)(n0 + l31) * C + ks * 16 + hi * 8);

    f32x16 o_acc[4];
#pragma unroll
    for (int ct = 0; ct < 4; ct++)
#pragma unroll
        for (int r = 0; r < 16; r++) o_acc[ct][r] = 0.0f;
    float L = 0.0f;

    // 512 threads: one uint4 of K + one of V per thread per tile
    uint4 kreg, vreg;
    const int km_ = t >> 4, kc8_ = (t & 15) << 3;   // K: 32 rows x 16 chunks
    const int vc_ = t >> 2, vm8_ = (t & 3) << 3;    // V: 128 rows x 4 chunks

#define ATT_LOAD(BLK)                                                                  \
    {                                                                                  \
        int mb_ = m_begin + (BLK) * 32;                                                \
        kreg = *reinterpret_cast<const uint4*>(K + (size_t)(mb_ + km_) * C + kc8_);    \
        vreg = *reinterpret_cast<const uint4*>(V + (size_t)vc_ * NSP + mb_ + vm8_);    \
    }

#define ATT_STORE(BUF)                                                                 \
    {                                                                                  \
        *reinterpret_cast<uint4*>(&Kl[BUF][km_ * 136 + kc8_]) = kreg;                  \
        *reinterpret_cast<uint4*>(&Vl[BUF][vc_ * 40 + vm8_]) = vreg;                   \
    }

    // prologue: tile 0 -> buf 0; prefetch tile 1 into regs
    ATT_LOAD(0);
    ATT_STORE(0);
    if (iters > 1) ATT_LOAD(1);
    __syncthreads();

    int cur = 0;
    for (int blk = 0; blk < iters; blk++) {
        const unsigned short* Kc = &Kl[cur][0];
        const unsigned short* Vc = &Vl[cur][0];

        // S^T[m][n] (32x32): A = K rows (m = l31), B = Q cols (n = l31)
        f32x16 s;
#pragma unroll
        for (int r = 0; r < 16; r++) s[r] = 0.0f;
        __builtin_amdgcn_s_setprio(1);
#pragma unroll
        for (int ks = 0; ks < 8; ks++) {
            short8 ka = *reinterpret_cast<const short8*>(&Kc[l31 * 136 + ks * 16 + hi * 8]);
            s = mfma32(ka, qf[ks], s);
        }
        __builtin_amdgcn_s_setprio(0);

        // mid-iter: commit tile blk+1 (regs) into buf cur^1, reissue loads for blk+2
        if (blk + 1 < iters) {
            ATT_STORE(cur ^ 1);
            if (blk + 2 < iters) ATT_LOAD(blk + 2);
        }

        // P = exp2(S) in place, accumulate L
        float ls = 0.0f;
#pragma unroll
        for (int r = 0; r < 16; r++) {
            s[r] = ex2(s[r]);
            ls += s[r];
        }
        L += ls;

        // in-register P -> PV B-fragments via permlane32_swap (T12)
        unsigned a0 = pkbf(s[0], s[1]),  a1 = pkbf(s[2], s[3]);
        unsigned b0 = pkbf(s[4], s[5]),  b1 = pkbf(s[6], s[7]);
        unsigned c0 = pkbf(s[8], s[9]),  c1 = pkbf(s[10], s[11]);
        unsigned d0 = pkbf(s[12], s[13]), d1 = pkbf(s[14], s[15]);
        asm("v_permlane32_swap_b32 %0, %1" : "+v"(a0), "+v"(b0));
        asm("v_permlane32_swap_b32 %0, %1" : "+v"(a1), "+v"(b1));
        asm("v_permlane32_swap_b32 %0, %1" : "+v"(c0), "+v"(d0));
        asm("v_permlane32_swap_b32 %0, %1" : "+v"(c1), "+v"(d1));
        union { uint4 u; short8 s8; } f0u, f1u;
        f0u.u = make_uint4(a0, a1, b0, b1);  // m =  0..15
        f1u.u = make_uint4(c0, c1, d0, d1);  // m = 16..31

        // O^T[c][n] += V[c][m] * P^T[m][n]
        __builtin_amdgcn_s_setprio(1);
#pragma unroll
        for (int ct = 0; ct < 4; ct++) {
            short8 v0 = *reinterpret_cast<const short8*>(&Vc[(ct * 32 + l31) * 40 + hi * 8]);
            short8 v1 = *reinterpret_cast<const short8*>(&Vc[(ct * 32 + l31) * 40 + 16 + hi * 8]);
            o_acc[ct] = mfma32(v0, f0u.s8, o_acc[ct]);
            o_acc[ct] = mfma32(v1, f1u.s8, o_acc[ct]);
        }
        __builtin_amdgcn_s_setprio(0);

        __syncthreads();
        cur ^= 1;
    }

#undef ATT_LOAD
#undef ATT_STORE

    // epilogue: L reduce + partial O store ([n][c] bf16)
    const size_t kjb = (size_t)(kc * 4 + jb);
    float Lv = L + __shfl_xor(L, 32);
    if (lane < 32) Lp[kjb * NSP + n0 + l31] = Lv;

    unsigned short* Ob = Op + kjb * NSP * C;  // [n][c]
    const int n = n0 + l31;
    unsigned short* On = Ob + (size_t)n * C + hi * 4;
#pragma unroll
    for (int ct = 0; ct < 4; ct++)
#pragma unroll
        for (int rb = 0; rb < 4; rb++) {
            int r0 = rb * 4;
            uint2 u;
            u.x = pkbf(o_acc[ct][r0 + 0], o_acc[ct][r0 + 1]);
            u.y = pkbf(o_acc[ct][r0 + 2], o_acc[ct][r0 + 3]);
            *reinterpret_cast<uint2*>(On + ct * 32 + rb * 8) = u;
        }
}

// ======================= output projection + residual (pass 1) =======================
__global__ __launch_bounds__(256)
void proj_kernel(const unsigned short* __restrict__ Op, const float* __restrict__ Lp, int nks,
                 const unsigned short* __restrict__ Wb,
                 const float* __restrict__ bo, int layer_base,
                 const float* __restrict__ res0, const float* __restrict__ res1,
                 float* __restrict__ out0, float* __restrict__ out1)
{
    __shared__ __align__(16) unsigned short Wl[128 * 136];
    __shared__ __align__(16) unsigned short Il[32 * 136];
    const int t = threadIdx.x;
    const int ntile = blockIdx.x, jb = blockIdx.y;
    const int job = jb >> 1, b = jb & 1, layer = layer_base + job;
    const float* bias = bo + layer * C;
    const float* res = (job ? res1 : res0) + (size_t)b * C * NSP;
    float* out = (job ? out1 : out0) + (size_t)b * C * NSP;
    const int n0 = ntile * 32;

    stage_wb(Wb + (size_t)(12 + layer) * 16384, Wl, t);
    stage_sum32(Op, Lp, jb, nks, n0, Il, t);
    __syncthreads();

    const int lane = t & 63, w = t >> 6, l15 = lane & 15, quad = lane >> 4;
    f32x4 acc[2][2];
#pragma unroll
    for (int ot = 0; ot < 2; ot++)
#pragma unroll
        for (int nt = 0; nt < 2; nt++)
#pragma unroll
            for (int r = 0; r < 4; r++) acc[ot][nt][r] = 0.0f;
#pragma unroll
    for (int ks = 0; ks < 4; ks++) {
        int co = ks * 32 + quad * 8;
        short8 a0 = *reinterpret_cast<const short8*>(&Wl[(w * 32 + l15) * 136 + co]);
        short8 a1 = *reinterpret_cast<const short8*>(&Wl[(w * 32 + 16 + l15) * 136 + co]);
#pragma unroll
        for (int nt = 0; nt < 2; nt++) {
            short8 bb = *reinterpret_cast<const short8*>(&Il[(nt * 16 + l15) * 136 + co]);
            acc[0][nt] = mfma16(a0, bb, acc[0][nt]);
            acc[1][nt] = mfma16(a1, bb, acc[1][nt]);
        }
    }
#pragma unroll
    for (int ot = 0; ot < 2; ot++)
#pragma unroll
        for (int r = 0; r < 4; r++) {
            int o = w * 32 + ot * 16 + quad * 4 + r;
            float bz = bias[o];
#pragma unroll
            for (int nt = 0; nt < 2; nt++) {
                int n = n0 + nt * 16 + l15;
                float v = fmaxf(acc[ot][nt][r] + bz, 0.0f) + res[(size_t)o * NSP + n];
                out[(size_t)o * NSP + n] = v;
            }
        }
}

// ======================= final: both jobs summed into d_out =======================
__global__ __launch_bounds__(256)
void final_kernel(const unsigned short* __restrict__ Op, const float* __restrict__ Lp, int nks,
                  const unsigned short* __restrict__ Wb,
                  const float* __restrict__ bo,
                  const float* __restrict__ fuse0, const float* __restrict__ fuse1,
                  float* __restrict__ out)
{
    __shared__ __align__(16) unsigned short Wl[128 * 136];
    __shared__ __align__(16) unsigned short Il[32 * 136];
    const int t = threadIdx.x;
    const int ntile = blockIdx.x, b = blockIdx.y;
    const int n0 = ntile * 32;
    const int lane = t & 63, w = t >> 6, l15 = lane & 15, quad = lane >> 4;

    float tot[2][2][4];
#pragma unroll
    for (int ot = 0; ot < 2; ot++)
#pragma unroll
        for (int nt = 0; nt < 2; nt++)
#pragma unroll
            for (int r = 0; r < 4; r++) tot[ot][nt][r] = 0.0f;

    for (int j = 0; j < 2; j++) {
        if (j) __syncthreads();
        int layer = 2 + j;
        stage_wb(Wb + (size_t)(12 + layer) * 16384, Wl, t);
        stage_sum32(Op, Lp, j * 2 + b, nks, n0, Il, t);
        __syncthreads();

        f32x4 acc[2][2];
#pragma unroll
        for (int ot = 0; ot < 2; ot++)
#pragma unroll
            for (int nt = 0; nt < 2; nt++)
#pragma unroll
                for (int r = 0; r < 4; r++) acc[ot][nt][r] = 0.0f;
#pragma unroll
        for (int ks = 0; ks < 4; ks++) {
            int co = ks * 32 + quad * 8;
            short8 a0 = *reinterpret_cast<const short8*>(&Wl[(w * 32 + l15) * 136 + co]);
            short8 a1 = *reinterpret_cast<const short8*>(&Wl[(w * 32 + 16 + l15) * 136 + co]);
#pragma unroll
            for (int nt = 0; nt < 2; nt++) {
                short8 bb = *reinterpret_cast<const short8*>(&Il[(nt * 16 + l15) * 136 + co]);
                acc[0][nt] = mfma16(a0, bb, acc[0][nt]);
                acc[1][nt] = mfma16(a1, bb, acc[1][nt]);
            }
        }
        const float* bias = bo + layer * C;
        const float* fuse = (j ? fuse1 : fuse0) + (size_t)b * C * NSP;
#pragma unroll
        for (int ot = 0; ot < 2; ot++)
#pragma unroll
            for (int r = 0; r < 4; r++) {
                int o = w * 32 + ot * 16 + quad * 4 + r;
                float bz = bias[o];
#pragma unroll
                for (int nt = 0; nt < 2; nt++) {
                    int n = n0 + nt * 16 + l15;
                    tot[ot][nt][r] += fmaxf(acc[ot][nt][r] + bz, 0.0f) + fuse[(size_t)o * NSP + n];
                }
            }
    }
#pragma unroll
    for (int ot = 0; ot < 2; ot++)
#pragma unroll
        for (int r = 0; r < 4; r++) {
            int o = w * 32 + ot * 16 + quad * 4 + r;
#pragma unroll
            for (int nt = 0; nt < 2; nt++) {
                int n = n0 + nt * 16 + l15;
                out[(size_t)b * C * NSP + (size_t)o * NSP + n] = tot[ot][nt][r];
            }
        }
}

extern "C" void kernel_launch(void* const* d_in, const int* in_sizes, int n_in,
                              void* d_out, int out_size, void* d_ws, size_t ws_size,
                              hipStream_t stream)
{
    (void)in_sizes; (void)n_in; (void)out_size;
    const float* x  = (const float*)d_in[0];
    const float* y  = (const float*)d_in[1];
    const float* Wq = (const float*)d_in[2];
    const float* bq = (const float*)d_in[3];
    const float* Wk = (const float*)d_in[4];
    const float* bk = (const float*)d_in[5];
    const float* Wv = (const float*)d_in[6];
    const float* bv = (const float*)d_in[7];
    const float* Wo = (const float*)d_in[8];
    const float* bo = (const float*)d_in[9];
    float* out = (float*)d_out;
    char* ws = (char*)d_ws;

    // split-K factor: ks=4 -> grid 16*4*4 = 256 WGs = one round at 1 WG/CU.
    int ks = (ws_size >= 38010880u) ? 4 : 2;
    int iters = 128 / ks;

    unsigned short* Qb = (unsigned short*)(ws);               // 4 MB [jb][n][c]
    unsigned short* Kb = (unsigned short*)(ws + (4u << 20));  // 4 MB [jb][n][c]
    unsigned short* Vb = (unsigned short*)(ws + (8u << 20));  // 4 MB [jb][c][n]
    unsigned short* Op = (unsigned short*)(ws + (12u << 20)); // ks*4 MB [k][jb][n][c] bf16
    size_t op_bytes = (size_t)ks * 4 * NSP * C * 2;
    float* Lp = (float*)(ws + (12u << 20) + op_bytes);        // ks*64 KB [k*4+jb][n]
    float* fuse0 = Lp + (size_t)ks * 4 * NSP;                 // 4 MB [b][c][n] fp32
    float* fuse1 = fuse0 + (size_t)2 * C * NSP;               // 4 MB
    unsigned short* Wb = (unsigned short*)(fuse1 + (size_t)2 * C * NSP);  // 512 KB bf16 x16 mats

    // weight pre-conversion (once per launch)
    prep_kernel<<<dim3(128), 256, 0, stream>>>(Wq, Wk, Wv, Wo, Wb);

    // pass 1: L0 (Q from x, KV from y), L1 (Q from y, KV from x)
    qkv_kernel<<<dim3(64, 3, 4), 256, 0, stream>>>(x, y, y, x, Wb, bq, bk, bv, 0,
                                                   Qb, Kb, Vb);
    attn_kernel<<<dim3(16, 4, ks), 512, 0, stream>>>(Qb, Kb, Vb, Op, Lp, iters);
    proj_kernel<<<dim3(128, 4), 256, 0, stream>>>(Op, Lp, ks, Wb, bo, 0, x, y, fuse0, fuse1);

    // pass 2: L2 (all from fuse_xy), L3 (all from fuse_yz)
    qkv_kernel<<<dim3(64, 3, 4), 256, 0, stream>>>(fuse0, fuse1, fuse0, fuse1, Wb,
                                                   bq, bk, bv, 2, Qb, Kb, Vb);
    attn_kernel<<<dim3(16, 4, ks), 512, 0, stream>>>(Qb, Kb, Vb, Op, Lp, iters);
    final_kernel<<<dim3(128, 2), 256, 0, stream>>>(Op, Lp, ks, Wb, bo, fuse0, fuse1, out);
}

// Round 15
// 183.858 us; speedup vs baseline: 1.2292x; 1.0128x over previous
//
#include <hip/hip_runtime.h>
#include <math.h>

#define C 128
#define NSP 4096  // H*W
#define LOG2E 1.4426950408889634f

typedef __attribute__((ext_vector_type(8))) short short8;
typedef __attribute__((ext_vector_type(4))) float f32x4;
typedef __attribute__((ext_vector_type(16))) float f32x16;

static __device__ __forceinline__ unsigned short f2bf(float f) {
    union { float f; unsigned u; } a; a.f = f;
    unsigned r = a.u + 0x7fffu + ((a.u >> 16) & 1u);
    return (unsigned short)(r >> 16);
}

static __device__ __forceinline__ float bf2f(unsigned short s) {
    union { unsigned u; float f; } a; a.u = (unsigned)s << 16;
    return a.f;
}

// pack two f32 -> bf16x2 (round-half-up); a in low16, b in high16
static __device__ __forceinline__ unsigned pkbf(float a, float b) {
    union { float f; unsigned u; } ua, ub; ua.f = a; ub.f = b;
    return __builtin_amdgcn_perm(ub.u + 0x8000u, ua.u + 0x8000u, 0x07060302u);
}

static __device__ __forceinline__ float ex2(float x) {
#if __has_builtin(__builtin_amdgcn_exp2f)
    return __builtin_amdgcn_exp2f(x);
#else
    return exp2f(x);
#endif
}

static __device__ __forceinline__ f32x4 mfma16(short8 a, short8 b, f32x4 c) {
    // D[row=quad*4+reg][col=lane&15]; A[row=lane&15][k=quad*8+j]; B[k=quad*8+j][col=lane&15]
    return __builtin_amdgcn_mfma_f32_16x16x32_bf16(a, b, c, 0, 0, 0);
}

static __device__ __forceinline__ f32x16 mfma32(short8 a, short8 b, f32x16 c) {
    // D[row=(r&3)+8*(r>>2)+4*(lane>>5)][col=lane&31]
    // A[row=lane&31][k=(lane>>5)*8+j]; B[k=(lane>>5)*8+j][col=lane&31]
    return __builtin_amdgcn_mfma_f32_32x32x16_bf16(a, b, c, 0, 0, 0);
}

// ======================= weight pre-conversion =======================
// All 16 CxC matrices (Wq*log2e, Wk, Wv, Wo x 4 layers) -> bf16 once.
__global__ __launch_bounds__(256)
void prep_kernel(const float* __restrict__ Wq, const float* __restrict__ Wk,
                 const float* __restrict__ Wv, const float* __restrict__ Wo,
                 unsigned short* __restrict__ Wb)
{
    int gid = blockIdx.x * 256 + threadIdx.x;  // 128 blocks -> 32768 threads x 8 elems
    int base = gid * 8;
    int mat = base >> 14;                      // 16384 elems per matrix
    int off = base & 16383;
    const float* src = (mat < 4)  ? (Wq + (size_t)mat * 16384)
                     : (mat < 8)  ? (Wk + (size_t)(mat - 4) * 16384)
                     : (mat < 12) ? (Wv + (size_t)(mat - 8) * 16384)
                                  : (Wo + (size_t)(mat - 12) * 16384);
    float scale = (mat < 4) ? LOG2E : 1.0f;
    float4 v0 = *reinterpret_cast<const float4*>(src + off);
    float4 v1 = *reinterpret_cast<const float4*>(src + off + 4);
    uint4 u;
    u.x = pkbf(v0.x * scale, v0.y * scale);
    u.y = pkbf(v0.z * scale, v0.w * scale);
    u.z = pkbf(v1.x * scale, v1.y * scale);
    u.w = pkbf(v1.z * scale, v1.w * scale);
    *reinterpret_cast<uint4*>(Wb + base) = u;
}

// ---- staging helpers ----
// pure uint4 copy of a pre-converted bf16 [128][128] weight matrix into Wl (pad 136)
static __device__ __forceinline__ void stage_wb(const unsigned short* __restrict__ Wm,
                                                unsigned short* __restrict__ Wl, int t) {
#pragma unroll
    for (int i = 0; i < 8; i++) {
        int idx = i * 256 + t;
        int o = idx >> 4, c8 = (idx & 15) << 3;
        *reinterpret_cast<uint4*>(&Wl[o * 136 + c8]) =
            *reinterpret_cast<const uint4*>(Wm + o * C + c8);
    }
}

// transpose-on-read input staging: In fp32 [c][n] -> Il bf16 [n][c] (pad 136).
// Lane-coalesced dword loads (lanes walk n), ONE b128 LDS write per 8 elems.
static __device__ __forceinline__ void stage_in(const float* __restrict__ In, int n0,
                                                unsigned short* __restrict__ Il, int t) {
#pragma unroll
    for (int i = 0; i < 4; i++) {
        int idx = i * 256 + t;
        int n = idx & 63, cb = idx >> 6;   // cb 0..15
        float v[8];
#pragma unroll
        for (int j = 0; j < 8; j++)
            v[j] = In[(size_t)(cb * 8 + j) * NSP + n0 + n];
        uint4 u;
        u.x = pkbf(v[0], v[1]);
        u.y = pkbf(v[2], v[3]);
        u.z = pkbf(v[4], v[5]);
        u.w = pkbf(v[6], v[7]);
        *reinterpret_cast<uint4*>(&Il[n * 136 + cb * 8]) = u;
    }
}

// fused combine+stage for a 32-row tile: Il[n][c] = bf16((sum_k Op_k)/(sum_k L_k))
static __device__ __forceinline__ void stage_sum32(const unsigned short* __restrict__ Op,
                                                   const float* __restrict__ Lp,
                                                   int jb, int nks, int n0,
                                                   unsigned short* __restrict__ Il, int t) {
#pragma unroll
    for (int i = 0; i < 2; i++) {
        int idx = i * 256 + t;
        int n = idx >> 4, c8 = (idx & 15) << 3;
        float o[8];
#pragma unroll
        for (int j = 0; j < 8; j++) o[j] = 0.0f;
        float Ls = 0.0f;
        for (int k = 0; k < nks; k++) {
            size_t kjb = (size_t)(k * 4 + jb);
            Ls += Lp[kjb * NSP + n0 + n];
            union { uint4 v; unsigned short s[8]; } u;
            u.v = *reinterpret_cast<const uint4*>(Op + (kjb * NSP + n0 + n) * C + c8);
#pragma unroll
            for (int j = 0; j < 8; j++) o[j] += bf2f(u.s[j]);
        }
        float inv = 1.0f / Ls;
        union { uint4 v; unsigned u[4]; } w;
        w.u[0] = pkbf(o[0] * inv, o[1] * inv);
        w.u[1] = pkbf(o[2] * inv, o[3] * inv);
        w.u[2] = pkbf(o[4] * inv, o[5] * inv);
        w.u[3] = pkbf(o[6] * inv, o[7] * inv);
        *reinterpret_cast<uint4*>(&Il[n * 136 + c8]) = w.v;
    }
}

// ======================= QKV projection =======================
// out = relu(W @ in + b).  Q,K stored [n][c] bf16 ; V stored [c][n] bf16.
// W pre-converted bf16 (Q pre-scaled by log2e); bias scaled at load for Q.
__global__ __launch_bounds__(256)
void qkv_kernel(const float* __restrict__ qs0, const float* __restrict__ qs1,
                const float* __restrict__ kv0, const float* __restrict__ kv1,
                const unsigned short* __restrict__ Wb,
                const float* __restrict__ bq, const float* __restrict__ bk,
                const float* __restrict__ bv,
                int layer_base,
                unsigned short* __restrict__ Qb, unsigned short* __restrict__ Kb,
                unsigned short* __restrict__ Vb)
{
    __shared__ __align__(16) unsigned short Wl[128 * 136];
    __shared__ __align__(16) unsigned short Il[64 * 136];
    const int t = threadIdx.x;
    const int ntile = blockIdx.x, kind = blockIdx.y, jb = blockIdx.z;
    const int job = jb >> 1, b = jb & 1, layer = layer_base + job;
    const float* src = (kind == 0) ? (job ? qs1 : qs0) : (job ? kv1 : kv0);
    const float* In = src + (size_t)b * C * NSP;
    const unsigned short* Wm = Wb + (size_t)(kind * 4 + layer) * 16384;
    const float* bias = ((kind == 0) ? bq : (kind == 1) ? bk : bv) + layer * C;
    unsigned short* Out = ((kind == 0) ? Qb : (kind == 1) ? Kb : Vb) + (size_t)jb * NSP * C;
    const float scale = (kind == 0) ? LOG2E : 1.0f;
    const int n0 = ntile * 64;

    stage_wb(Wm, Wl, t);
    stage_in(In, n0, Il, t);
    __syncthreads();

    const int lane = t & 63, w = t >> 6, l15 = lane & 15, quad = lane >> 4;

    if (kind <= 1) {
        f32x4 acc[4][2];
#pragma unroll
        for (int nt = 0; nt < 4; nt++)
#pragma unroll
            for (int ot = 0; ot < 2; ot++)
#pragma unroll
                for (int r = 0; r < 4; r++) acc[nt][ot][r] = 0.0f;
#pragma unroll
        for (int ks = 0; ks < 4; ks++) {
            int co = ks * 32 + quad * 8;
            short8 b0 = *reinterpret_cast<const short8*>(&Wl[(w * 32 + l15) * 136 + co]);
            short8 b1 = *reinterpret_cast<const short8*>(&Wl[(w * 32 + 16 + l15) * 136 + co]);
#pragma unroll
            for (int nt = 0; nt < 4; nt++) {
                short8 a = *reinterpret_cast<const short8*>(&Il[(nt * 16 + l15) * 136 + co]);
                acc[nt][0] = mfma16(a, b0, acc[nt][0]);
                acc[nt][1] = mfma16(a, b1, acc[nt][1]);
            }
        }
        float bz0 = bias[w * 32 + l15] * scale;
        float bz1 = bias[w * 32 + 16 + l15] * scale;
#pragma unroll
        for (int nt = 0; nt < 4; nt++)
#pragma unroll
            for (int ot = 0; ot < 2; ot++)
#pragma unroll
                for (int r = 0; r < 4; r++) {
                    float v = fmaxf(acc[nt][ot][r] + (ot ? bz1 : bz0), 0.0f);
                    int n = n0 + nt * 16 + quad * 4 + r;
                    int o = w * 32 + ot * 16 + l15;
                    Out[(size_t)n * C + o] = f2bf(v);
                }
    } else {
        f32x4 acc[2][4];
#pragma unroll
        for (int ot = 0; ot < 2; ot++)
#pragma unroll
            for (int nt = 0; nt < 4; nt++)
#pragma unroll
                for (int r = 0; r < 4; r++) acc[ot][nt][r] = 0.0f;
#pragma unroll
        for (int ks = 0; ks < 4; ks++) {
            int co = ks * 32 + quad * 8;
            short8 a0 = *reinterpret_cast<const short8*>(&Wl[(w * 32 + l15) * 136 + co]);
            short8 a1 = *reinterpret_cast<const short8*>(&Wl[(w * 32 + 16 + l15) * 136 + co]);
#pragma unroll
            for (int nt = 0; nt < 4; nt++) {
                short8 bb = *reinterpret_cast<const short8*>(&Il[(nt * 16 + l15) * 136 + co]);
                acc[0][nt] = mfma16(a0, bb, acc[0][nt]);
                acc[1][nt] = mfma16(a1, bb, acc[1][nt]);
            }
        }
#pragma unroll
        for (int ot = 0; ot < 2; ot++)
#pragma unroll
            for (int r = 0; r < 4; r++) {
                int o = w * 32 + ot * 16 + quad * 4 + r;
                float bz = bias[o];
#pragma unroll
                for (int nt = 0; nt < 4; nt++) {
                    float v = fmaxf(acc[ot][nt][r] + bz, 0.0f);
                    Out[(size_t)o * NSP + n0 + nt * 16 + l15] = f2bf(v);
                }
            }
    }
}

// ======================= attention, no-max softmax, split-K over keys =======================
// R13's verified compute body (8 waves/512 thr, KVBLK=32, 32x32 MFMA,
// in-register P via permlane32_swap), with a 4-BUFFER LDS ROTATION and a
// barrier every 2 iterations (16 instead of 32). Schedule: iter b reads buf
// b%4; stores reg-tile (b+2) into buf (b+2)%4; loads tile b+3; barrier after
// odd iters. Invariant (verified case-by-case): the end-of-odd barrier bounds
// wave drift to <2 iters, so every buf read was stored >=2 iters ago (RAW ok)
// and every buf stored was last read >=2 iters ago (WAR ok). Register tile
// stays SINGLE kreg/vreg (R12's spill came from doubling registers, not LDS).
__global__ __launch_bounds__(512)
void attn_kernel(const unsigned short* __restrict__ Qb, const unsigned short* __restrict__ Kb,
                 const unsigned short* __restrict__ Vb, unsigned short* __restrict__ Op,
                 float* __restrict__ Lp, int iters)
{
    __shared__ __align__(16) unsigned short Kl[4][32 * 136];   // 4 x 8704 B  [m][c]
    __shared__ __align__(16) unsigned short Vl[4][128 * 40];   // 4 x 10240 B [c][m]
    const int t = threadIdx.x, lane = t & 63;
    const int l31 = lane & 31, hi = lane >> 5;

    // XCD-bijective swizzle (nwg = 16*4*ks, divisible by 8), jb-outer/kc-inner
    const int ksz = gridDim.z;
    const int nwg = gridDim.x * gridDim.y * ksz;
    const int linear = blockIdx.x + gridDim.x * (blockIdx.y + gridDim.y * blockIdx.z);
    const int cpx = nwg >> 3;
    const int wid = (linear & 7) * cpx + (linear >> 3);
    const int ntile = wid & 15;
    const int r2 = wid >> 4;
    const int jb = r2 / ksz, kc = r2 % ksz;

    const int n0 = ntile * 256 + (t >> 6) * 32;
    const int m_begin = kc * iters * 32;
    const unsigned short* Q = Qb + (size_t)jb * NSP * C;
    const unsigned short* K = Kb + (size_t)jb * NSP * C;
    const unsigned short* V = Vb + (size_t)jb * NSP * C;  // [c][n]

    // Q fragments (B-operand of S): B[k=hi*8+j][col=n=l31], k = channel
    short8 qf[8];
#pragma unroll
    for (int ks = 0; ks < 8; ks++)
        qf[ks] = *reinterpret_cast<const short8*>(
            Q + (size_t)(n0 + l31) * C + ks * 16 + hi * 8);

    f32x16 o_acc[4];
#pragma unroll
    for (int ct = 0; ct < 4; ct++)
#pragma unroll
        for (int r = 0; r < 16; r++) o_acc[ct][r] = 0.0f;
    float L = 0.0f;

    // 512 threads: one uint4 of K + one of V per thread per tile
    uint4 kreg, vreg;
    const int km_ = t >> 4, kc8_ = (t & 15) << 3;   // K: 32 rows x 16 chunks
    const int vc_ = t >> 2, vm8_ = (t & 3) << 3;    // V: 128 rows x 4 chunks

#define ATT_LOAD(BLK)                                                                  \
    {                                                                                  \
        int mb_ = m_begin + (BLK) * 32;                                                \
        kreg = *reinterpret_cast<const uint4*>(K + (size_t)(mb_ + km_) * C + kc8_);    \
        vreg = *reinterpret_cast<const uint4*>(V + (size_t)vc_ * NSP + mb_ + vm8_);    \
    }

#define ATT_STORE(BUF)                                                                 \
    {                                                                                  \
        *reinterpret_cast<uint4*>(&Kl[BUF][km_ * 136 + kc8_]) = kreg;                  \
        *reinterpret_cast<uint4*>(&Vl[BUF][vc_ * 40 + vm8_]) = vreg;                   \
    }

    // prologue: tiles 0,1 -> bufs 0,1; tile 2 in regs
    ATT_LOAD(0);
    ATT_STORE(0);
    if (iters > 1) { ATT_LOAD(1); ATT_STORE(1); }
    if (iters > 2) ATT_LOAD(2);
    __syncthreads();

    for (int blk = 0; blk < iters; blk++) {
        const unsigned short* Kc = &Kl[blk & 3][0];
        const unsigned short* Vc = &Vl[blk & 3][0];

        // S^T[m][n] (32x32): A = K rows (m = l31), B = Q cols (n = l31)
        f32x16 s;
#pragma unroll
        for (int r = 0; r < 16; r++) s[r] = 0.0f;
        __builtin_amdgcn_s_setprio(1);
#pragma unroll
        for (int ks = 0; ks < 8; ks++) {
            short8 ka = *reinterpret_cast<const short8*>(&Kc[l31 * 136 + ks * 16 + hi * 8]);
            s = mfma32(ka, qf[ks], s);
        }
        __builtin_amdgcn_s_setprio(0);

        // mid-iter: commit reg-tile blk+2 into buf (blk+2)%4 (its last readers
        // finished at iter blk-2, covered by the previous barrier), then issue
        // loads for tile blk+3 (consumed at iter blk+1's store).
        if (blk + 2 < iters) {
            ATT_STORE((blk + 2) & 3);
            if (blk + 3 < iters) ATT_LOAD(blk + 3);
        }

        // P = exp2(S) in place, accumulate L
        float ls = 0.0f;
#pragma unroll
        for (int r = 0; r < 16; r++) {
            s[r] = ex2(s[r]);
            ls += s[r];
        }
        L += ls;

        // in-register P -> PV B-fragments via permlane32_swap (T12)
        unsigned a0 = pkbf(s[0], s[1]),  a1 = pkbf(s[2], s[3]);
        unsigned b0 = pkbf(s[4], s[5]),  b1 = pkbf(s[6], s[7]);
        unsigned c0 = pkbf(s[8], s[9]),  c1 = pkbf(s[10], s[11]);
        unsigned d0 = pkbf(s[12], s[13]), d1 = pkbf(s[14], s[15]);
        asm("v_permlane32_swap_b32 %0, %1" : "+v"(a0), "+v"(b0));
        asm("v_permlane32_swap_b32 %0, %1" : "+v"(a1), "+v"(b1));
        asm("v_permlane32_swap_b32 %0, %1" : "+v"(c0), "+v"(d0));
        asm("v_permlane32_swap_b32 %0, %1" : "+v"(c1), "+v"(d1));
        union { uint4 u; short8 s8; } f0u, f1u;
        f0u.u = make_uint4(a0, a1, b0, b1);  // m =  0..15
        f1u.u = make_uint4(c0, c1, d0, d1);  // m = 16..31

        // O^T[c][n] += V[c][m] * P^T[m][n]
        __builtin_amdgcn_s_setprio(1);
#pragma unroll
        for (int ct = 0; ct < 4; ct++) {
            short8 v0 = *reinterpret_cast<const short8*>(&Vc[(ct * 32 + l31) * 40 + hi * 8]);
            short8 v1 = *reinterpret_cast<const short8*>(&Vc[(ct * 32 + l31) * 40 + 16 + hi * 8]);
            o_acc[ct] = mfma32(v0, f0u.s8, o_acc[ct]);
            o_acc[ct] = mfma32(v1, f1u.s8, o_acc[ct]);
        }
        __builtin_amdgcn_s_setprio(0);

        // barrier every 2 iters (after odd iters): bounds wave drift to <2 iters
        if (blk & 1) __syncthreads();
    }

#undef ATT_LOAD
#undef ATT_STORE

    // epilogue: L reduce + partial O store ([n][c] bf16)
    const size_t kjb = (size_t)(kc * 4 + jb);
    float Lv = L + __shfl_xor(L, 32);
    if (lane < 32) Lp[kjb * NSP + n0 + l31] = Lv;

    unsigned short* Ob = Op + kjb * NSP * C;  // [n][c]
    const int n = n0 + l31;
    unsigned short* On = Ob + (size_t)n * C + hi * 4;
#pragma unroll
    for (int ct = 0; ct < 4; ct++)
#pragma unroll
        for (int rb = 0; rb < 4; rb++) {
            int r0 = rb * 4;
            uint2 u;
            u.x = pkbf(o_acc[ct][r0 + 0], o_acc[ct][r0 + 1]);
            u.y = pkbf(o_acc[ct][r0 + 2], o_acc[ct][r0 + 3]);
            *reinterpret_cast<uint2*>(On + ct * 32 + rb * 8) = u;
        }
}

// ======================= output projection + residual (pass 1) =======================
__global__ __launch_bounds__(256)
void proj_kernel(const unsigned short* __restrict__ Op, const float* __restrict__ Lp, int nks,
                 const unsigned short* __restrict__ Wb,
                 const float* __restrict__ bo, int layer_base,
                 const float* __restrict__ res0, const float* __restrict__ res1,
                 float* __restrict__ out0, float* __restrict__ out1)
{
    __shared__ __align__(16) unsigned short Wl[128 * 136];
    __shared__ __align__(16) unsigned short Il[32 * 136];
    const int t = threadIdx.x;
    const int ntile = blockIdx.x, jb = blockIdx.y;
    const int job = jb >> 1, b = jb & 1, layer = layer_base + job;
    const float* bias = bo + layer * C;
    const float* res = (job ? res1 : res0) + (size_t)b * C * NSP;
    float* out = (job ? out1 : out0) + (size_t)b * C * NSP;
    const int n0 = ntile * 32;

    stage_wb(Wb + (size_t)(12 + layer) * 16384, Wl, t);
    stage_sum32(Op, Lp, jb, nks, n0, Il, t);
    __syncthreads();

    const int lane = t & 63, w = t >> 6, l15 = lane & 15, quad = lane >> 4;
    f32x4 acc[2][2];
#pragma unroll
    for (int ot = 0; ot < 2; ot++)
#pragma unroll
        for (int nt = 0; nt < 2; nt++)
#pragma unroll
            for (int r = 0; r < 4; r++) acc[ot][nt][r] = 0.0f;
#pragma unroll
    for (int ks = 0; ks < 4; ks++) {
        int co = ks * 32 + quad * 8;
        short8 a0 = *reinterpret_cast<const short8*>(&Wl[(w * 32 + l15) * 136 + co]);
        short8 a1 = *reinterpret_cast<const short8*>(&Wl[(w * 32 + 16 + l15) * 136 + co]);
#pragma unroll
        for (int nt = 0; nt < 2; nt++) {
            short8 bb = *reinterpret_cast<const short8*>(&Il[(nt * 16 + l15) * 136 + co]);
            acc[0][nt] = mfma16(a0, bb, acc[0][nt]);
            acc[1][nt] = mfma16(a1, bb, acc[1][nt]);
        }
    }
#pragma unroll
    for (int ot = 0; ot < 2; ot++)
#pragma unroll
        for (int r = 0; r < 4; r++) {
            int o = w * 32 + ot * 16 + quad * 4 + r;
            float bz = bias[o];
#pragma unroll
            for (int nt = 0; nt < 2; nt++) {
                int n = n0 + nt * 16 + l15;
                float v = fmaxf(acc[ot][nt][r] + bz, 0.0f) + res[(size_t)o * NSP + n];
                out[(size_t)o * NSP + n] = v;
            }
        }
}

// ======================= final: both jobs summed into d_out =======================
__global__ __launch_bounds__(256)
void final_kernel(const unsigned short* __restrict__ Op, const float* __restrict__ Lp, int nks,
                  const unsigned short* __restrict__ Wb,
                  const float* __restrict__ bo,
                  const float* __restrict__ fuse0, const float* __restrict__ fuse1,
                  float* __restrict__ out)
{
    __shared__ __align__(16) unsigned short Wl[128 * 136];
    __shared__ __align__(16) unsigned short Il[32 * 136];
    const int t = threadIdx.x;
    const int ntile = blockIdx.x, b = blockIdx.y;
    const int n0 = ntile * 32;
    const int lane = t & 63, w = t >> 6, l15 = lane & 15, quad = lane >> 4;

    float tot[2][2][4];
#pragma unroll
    for (int ot = 0; ot < 2; ot++)
#pragma unroll
        for (int nt = 0; nt < 2; nt++)
#pragma unroll
            for (int r = 0; r < 4; r++) tot[ot][nt][r] = 0.0f;

    for (int j = 0; j < 2; j++) {
        if (j) __syncthreads();
        int layer = 2 + j;
        stage_wb(Wb + (size_t)(12 + layer) * 16384, Wl, t);
        stage_sum32(Op, Lp, j * 2 + b, nks, n0, Il, t);
        __syncthreads();

        f32x4 acc[2][2];
#pragma unroll
        for (int ot = 0; ot < 2; ot++)
#pragma unroll
            for (int nt = 0; nt < 2; nt++)
#pragma unroll
                for (int r = 0; r < 4; r++) acc[ot][nt][r] = 0.0f;
#pragma unroll
        for (int ks = 0; ks < 4; ks++) {
            int co = ks * 32 + quad * 8;
            short8 a0 = *reinterpret_cast<const short8*>(&Wl[(w * 32 + l15) * 136 + co]);
            short8 a1 = *reinterpret_cast<const short8*>(&Wl[(w * 32 + 16 + l15) * 136 + co]);
#pragma unroll
            for (int nt = 0; nt < 2; nt++) {
                short8 bb = *reinterpret_cast<const short8*>(&Il[(nt * 16 + l15) * 136 + co]);
                acc[0][nt] = mfma16(a0, bb, acc[0][nt]);
                acc[1][nt] = mfma16(a1, bb, acc[1][nt]);
            }
        }
        const float* bias = bo + layer * C;
        const float* fuse = (j ? fuse1 : fuse0) + (size_t)b * C * NSP;
#pragma unroll
        for (int ot = 0; ot < 2; ot++)
#pragma unroll
            for (int r = 0; r < 4; r++) {
                int o = w * 32 + ot * 16 + quad * 4 + r;
                float bz = bias[o];
#pragma unroll
                for (int nt = 0; nt < 2; nt++) {
                    int n = n0 + nt * 16 + l15;
                    tot[ot][nt][r] += fmaxf(acc[ot][nt][r] + bz, 0.0f) + fuse[(size_t)o * NSP + n];
                }
            }
    }
#pragma unroll
    for (int ot = 0; ot < 2; ot++)
#pragma unroll
        for (int r = 0; r < 4; r++) {
            int o = w * 32 + ot * 16 + quad * 4 + r;
#pragma unroll
            for (int nt = 0; nt < 2; nt++) {
                int n = n0 + nt * 16 + l15;
                out[(size_t)b * C * NSP + (size_t)o * NSP + n] = tot[ot][nt][r];
            }
        }
}

extern "C" void kernel_launch(void* const* d_in, const int* in_sizes, int n_in,
                              void* d_out, int out_size, void* d_ws, size_t ws_size,
                              hipStream_t stream)
{
    (void)in_sizes; (void)n_in; (void)out_size;
    const float* x  = (const float*)d_in[0];
    const float* y  = (const float*)d_in[1];
    const float* Wq = (const float*)d_in[2];
    const float* bq = (const float*)d_in[3];
    const float* Wk = (const float*)d_in[4];
    const float* bk = (const float*)d_in[5];
    const float* Wv = (const float*)d_in[6];
    const float* bv = (const float*)d_in[7];
    const float* Wo = (const float*)d_in[8];
    const float* bo = (const float*)d_in[9];
    float* out = (float*)d_out;
    char* ws = (char*)d_ws;

    // split-K factor: ks=4 -> grid 16*4*4 = 256 WGs = one round at 1 WG/CU.
    int ks = (ws_size >= 38010880u) ? 4 : 2;
    int iters = 128 / ks;

    unsigned short* Qb = (unsigned short*)(ws);               // 4 MB [jb][n][c]
    unsigned short* Kb = (unsigned short*)(ws + (4u << 20));  // 4 MB [jb][n][c]
    unsigned short* Vb = (unsigned short*)(ws + (8u << 20));  // 4 MB [jb][c][n]
    unsigned short* Op = (unsigned short*)(ws + (12u << 20)); // ks*4 MB [k][jb][n][c] bf16
    size_t op_bytes = (size_t)ks * 4 * NSP * C * 2;
    float* Lp = (float*)(ws + (12u << 20) + op_bytes);        // ks*64 KB [k*4+jb][n]
    float* fuse0 = Lp + (size_t)ks * 4 * NSP;                 // 4 MB [b][c][n] fp32
    float* fuse1 = fuse0 + (size_t)2 * C * NSP;               // 4 MB
    unsigned short* Wb = (unsigned short*)(fuse1 + (size_t)2 * C * NSP);  // 512 KB bf16 x16 mats

    // weight pre-conversion (once per launch)
    prep_kernel<<<dim3(128), 256, 0, stream>>>(Wq, Wk, Wv, Wo, Wb);

    // pass 1: L0 (Q from x, KV from y), L1 (Q from y, KV from x)
    qkv_kernel<<<dim3(64, 3, 4), 256, 0, stream>>>(x, y, y, x, Wb, bq, bk, bv, 0,
                                                   Qb, Kb, Vb);
    attn_kernel<<<dim3(16, 4, ks), 512, 0, stream>>>(Qb, Kb, Vb, Op, Lp, iters);
    proj_kernel<<<dim3(128, 4), 256, 0, stream>>>(Op, Lp, ks, Wb, bo, 0, x, y, fuse0, fuse1);

    // pass 2: L2 (all from fuse_xy), L3 (all from fuse_yz)
    qkv_kernel<<<dim3(64, 3, 4), 256, 0, stream>>>(fuse0, fuse1, fuse0, fuse1, Wb,
                                                   bq, bk, bv, 2, Qb, Kb, Vb);
    attn_kernel<<<dim3(16, 4, ks), 512, 0, stream>>>(Qb, Kb, Vb, Op, Lp, iters);
    final_kernel<<<dim3(128, 2), 256, 0, stream>>>(Op, Lp, ks, Wb, bo, fuse0, fuse1, out);
}